// Round 8
// baseline (404.345 us; speedup 1.0000x reference)
//
#include <hip/hip_runtime.h>
#include <math.h>

// Problem constants
#define BB   4
#define LL   4096
#define CC   512
#define GG   4
#define HH   16
#define KW   5      // conv kernel / offset range factor
#define GCC  128    // C / G
#define HCC  32     // C / H
#define BGN  (BB*GG)   // 16
#define BHN  (BB*HH)   // 64
#define KSPLIT 16

typedef __attribute__((ext_vector_type(8))) __bf16 bf16x8;
typedef __attribute__((ext_vector_type(4))) float f32x4;

// ---------------------------------------------------------------------------
// bf16 split helpers (manual RNE, no header-struct dependence)
// ---------------------------------------------------------------------------
__device__ __forceinline__ unsigned int f2bf_bits(float f) {
    unsigned int u = __float_as_uint(f);
    return (u + 0x7FFFu + ((u >> 16) & 1u)) >> 16;
}
__device__ __forceinline__ float bfbits2f(unsigned int s) {
    return __uint_as_float(s << 16);
}
__device__ __forceinline__ void split2(float v, unsigned short& h, unsigned short& l) {
    unsigned int hb = f2bf_bits(v);
    float hf = bfbits2f(hb);
    unsigned int lb = f2bf_bits(v - hf);
    h = (unsigned short)hb; l = (unsigned short)lb;
}

__device__ __forceinline__ void gload16(const void* g, void* l) {
    __builtin_amdgcn_global_load_lds(
        (const __attribute__((address_space(1))) void*)g,
        (__attribute__((address_space(3))) void*)l, 16, 0, 0);
}

// ---------------------------------------------------------------------------
// split fp32 -> (bf16 hi, bf16 lo), vectorized x4
// ---------------------------------------------------------------------------
__global__ __launch_bounds__(256) void split_x_kernel(
    const float* __restrict__ in, unsigned short* __restrict__ hi,
    unsigned short* __restrict__ lo, int n4)
{
    int i = blockIdx.x * 256 + threadIdx.x;
    if (i >= n4) return;
    float4 v = ((const float4*)in)[i];
    ushort4 h, l;
    split2(v.x, h.x, l.x); split2(v.y, h.y, l.y);
    split2(v.z, h.z, l.z); split2(v.w, h.w, l.w);
    ((ushort4*)hi)[i] = h;
    ((ushort4*)lo)[i] = l;
}

// 4 weight matrices [512x512] each -> hi/lo segments of 262144 elements
__global__ __launch_bounds__(256) void split_w_kernel(
    const float* __restrict__ W0, const float* __restrict__ W1,
    const float* __restrict__ W2, const float* __restrict__ W3,
    unsigned short* __restrict__ hi, unsigned short* __restrict__ lo)
{
    int w = blockIdx.y;
    const float* W = (w == 0) ? W0 : (w == 1) ? W1 : (w == 2) ? W2 : W3;
    size_t seg4 = (size_t)w * 65536;   // 262144/4
    int i = blockIdx.x * 256 + threadIdx.x;   // x4 elements
    float4 v = ((const float4*)W)[i];
    ushort4 h, l;
    split2(v.x, h.x, l.x); split2(v.y, h.y, l.y);
    split2(v.z, h.z, l.z); split2(v.w, h.w, l.w);
    ((ushort4*)hi)[seg4 + i] = h;
    ((ushort4*)lo)[seg4 + i] = l;
}

// ---------------------------------------------------------------------------
// Split-bf16 MFMA GEMM:  D[b][r][c] = sum_k A[b?][r,k]*B[b?][c,k]
// 128x128 tile, BK=32, 256 thr (4 waves 2x2, each 64x64 = 4x4 frags 16x16).
// 3 MFMAs per (fi,fj) k-step: hi*hi + lo*hi + hi*lo.
// 2-phase LDS double-buffer (one barrier per K-step; next tile's
// global_load_lds issued between ds_reads and MFMA so HBM/L2 latency hides
// under compute) + XOR chunk swizzle (slot = chunk ^ ((row>>1)&3), applied
// as pre-swizzled GLOBAL source + swizzled ds_read addr; LDS dest linear
// per gload_lds constraint). Removes the ~4-way ds_read_b128 bank conflict.
// ---------------------------------------------------------------------------
__global__ __launch_bounds__(256) void gemm_split_mfma(
    const unsigned short* __restrict__ Ahi, const unsigned short* __restrict__ Alo,
    const unsigned short* __restrict__ Bhi, const unsigned short* __restrict__ Blo,
    const float* __restrict__ bias, const float* __restrict__ rpb,
    float* __restrict__ out, int RA, int RB, int Kd,
    size_t aStride, size_t bStride, int biasOnCol)
{
    __shared__ unsigned short sm[2][4][4096];   // [buf][Ah,Al,Bh,Bl][128*32] = 64 KB

    const int b  = blockIdx.z;
    const int c0 = blockIdx.x * 128;
    const int r0 = blockIdx.y * 128;

    const int tid  = threadIdx.x;
    const int lane = tid & 63;
    const int wv   = tid >> 6;
    const int wr   = wv >> 1, wc = wv & 1;

    // staging: wave wv covers tile rows [wv*32, wv*32+32); 2 instr/matrix.
    // source chunk pre-swizzled: schunk = c ^ ((srow>>1)&3)
    const int srow   = lane >> 2;
    const int schunk = (lane & 3) ^ ((lane >> 3) & 3);
    const size_t laneA = (size_t)(r0 + wv * 32 + srow) * Kd + (size_t)(schunk * 8);
    const size_t laneB = (size_t)(c0 + wv * 32 + srow) * Kd + (size_t)(schunk * 8);
    const unsigned short* gAh = Ahi + (size_t)b * aStride + laneA;
    const unsigned short* gAl = Alo + (size_t)b * aStride + laneA;
    const unsigned short* gBh = Bhi + (size_t)b * bStride + laneB;
    const unsigned short* gBl = Blo + (size_t)b * bStride + laneB;
    const size_t rowskip = (size_t)16 * Kd;
    const int ldsOff = wv * 1024;               // 32 rows * 32 u16

    // fragment read: slot = kblk ^ ((row>>1)&3); row-dependent part reduces
    // to (lane>>1)&3 for all fi (wr*64, fi*16 are 0 mod 8).
    const int lr = lane & 15;
    const int kx = ((lane >> 4) ^ ((lane >> 1) & 3)) * 8;
    const int aOff = (wr * 64 + lr) * 32 + kx;
    const int bOff = (wc * 64 + lr) * 32 + kx;

    f32x4 acc[4][4];
#pragma unroll
    for (int i = 0; i < 4; ++i)
#pragma unroll
        for (int j = 0; j < 4; ++j) acc[i][j] = (f32x4){0.f, 0.f, 0.f, 0.f};

    bf16x8 ah[4], al[4], bh[4], bl[4];

#define STAGE(buf, k0)                                                        \
    {                                                                         \
        unsigned short* d0 = &sm[buf][0][ldsOff];                             \
        gload16(gAh + (k0), d0);  gload16(gAh + (k0) + rowskip, d0 + 512);    \
        unsigned short* d1 = &sm[buf][1][ldsOff];                             \
        gload16(gAl + (k0), d1);  gload16(gAl + (k0) + rowskip, d1 + 512);    \
        unsigned short* d2 = &sm[buf][2][ldsOff];                             \
        gload16(gBh + (k0), d2);  gload16(gBh + (k0) + rowskip, d2 + 512);    \
        unsigned short* d3 = &sm[buf][3][ldsOff];                             \
        gload16(gBl + (k0), d3);  gload16(gBl + (k0) + rowskip, d3 + 512);    \
    }

#define LOADF(buf)                                                            \
    {                                                                         \
        const unsigned short* mAh = &sm[buf][0][aOff];                        \
        const unsigned short* mAl = &sm[buf][1][aOff];                        \
        const unsigned short* mBh = &sm[buf][2][bOff];                        \
        const unsigned short* mBl = &sm[buf][3][bOff];                        \
        _Pragma("unroll")                                                     \
        for (int i = 0; i < 4; ++i) {                                         \
            ah[i] = *(const bf16x8*)(mAh + i * 512);                          \
            al[i] = *(const bf16x8*)(mAl + i * 512);                          \
        }                                                                     \
        _Pragma("unroll")                                                     \
        for (int j = 0; j < 4; ++j) {                                         \
            bh[j] = *(const bf16x8*)(mBh + j * 512);                          \
            bl[j] = *(const bf16x8*)(mBl + j * 512);                          \
        }                                                                     \
    }

#define DOMFMA                                                                \
    {                                                                         \
        _Pragma("unroll")                                                     \
        for (int i = 0; i < 4; ++i)                                           \
            _Pragma("unroll")                                                 \
            for (int j = 0; j < 4; ++j) {                                     \
                acc[i][j] = __builtin_amdgcn_mfma_f32_16x16x32_bf16(ah[i], bh[j], acc[i][j], 0, 0, 0); \
                acc[i][j] = __builtin_amdgcn_mfma_f32_16x16x32_bf16(al[i], bh[j], acc[i][j], 0, 0, 0); \
                acc[i][j] = __builtin_amdgcn_mfma_f32_16x16x32_bf16(ah[i], bl[j], acc[i][j], 0, 0, 0); \
            }                                                                 \
    }

    // prologue: fill buffer 0; __syncthreads drains vmcnt -> tile resident
    STAGE(0, 0)
    __syncthreads();

    int cur = 0;
    for (int k0 = 0; k0 + 32 < Kd; k0 += 32) {
        LOADF(cur)                 // ds_reads of current tile (before any VMEM)
        STAGE(cur ^ 1, k0 + 32)    // prefetch next tile; flies during MFMA
        DOMFMA
        __syncthreads();           // drains vmcnt+lgkm: next tile ready, cur free
        cur ^= 1;
    }
    LOADF(cur)                     // last tile: no prefetch
    DOMFMA

#undef STAGE
#undef LOADF
#undef DOMFMA

    // epilogue: C/D layout col=lane&15, row=(lane>>4)*4+reg  [m89 verified]
    const int lg4 = (lane >> 4) * 4;
    float bcol[4];
#pragma unroll
    for (int fj = 0; fj < 4; ++fj)
        bcol[fj] = biasOnCol ? bias[c0 + wc * 64 + fj * 16 + lr] : 0.f;

#pragma unroll
    for (int fi = 0; fi < 4; ++fi) {
#pragma unroll
        for (int reg = 0; reg < 4; ++reg) {
            const int r = r0 + wr * 64 + fi * 16 + lg4 + reg;
            const float br = biasOnCol ? 0.f : bias[r];
            float* orow = out + ((size_t)b * RA + r) * RB + c0;
            const float* prow = rpb ? (rpb + (size_t)r * RB + c0) : nullptr;
#pragma unroll
            for (int fj = 0; fj < 4; ++fj) {
                const int c = wc * 64 + fj * 16 + lr;
                float val = acc[fi][fj][reg] + br + bcol[fj];
                if (prow) val += prow[c];
                orow[c] = val;
            }
        }
    }
}

// ---------------------------------------------------------------------------
// Fuse the two offset convs (linear, no activation between)
// ---------------------------------------------------------------------------
__global__ void comb_weights(const float* __restrict__ Woff1, const float* __restrict__ boff1,
                             const float* __restrict__ Woff2, const float* __restrict__ boff2,
                             float* __restrict__ wc)
{
    int idx = blockIdx.x * 256 + threadIdx.x;
    if (idx < GCC * KW) {
        int cp = idx / KW, t = idx - cp * KW;
        float s = 0.f;
        for (int c = 0; c < GCC; ++c)
            s = fmaf(Woff2[c], Woff1[((size_t)c * GCC + cp) * KW + t], s);
        wc[idx] = s;
    } else if (idx == GCC * KW) {
        float s = boff2[0];
        for (int c = 0; c < GCC; ++c) s = fmaf(Woff2[c], boff1[c], s);
        wc[idx] = s;
    } else if (idx == GCC * KW + 1) {
        wc[idx] = boff2[0];
    }
}

// ---------------------------------------------------------------------------
// Offsets stage 1: channel-split conv partials.
// ---------------------------------------------------------------------------
#define OLT 128
__global__ __launch_bounds__(128) void offsets_part_kernel(
    const float* __restrict__ q, const float* __restrict__ wc,
    float* __restrict__ part)
{
    __shared__ float sq[32][140];   // cols 0..135 used; pos = l0-8+col
    __shared__ float sw[32 * KW];

    const int l0 = blockIdx.x * OLT;
    const int bg = blockIdx.y;
    const int cg = blockIdx.z;
    const int tid = threadIdx.x;

    const float* qb = q + ((size_t)bg * GCC + cg * 32) * LL;

    for (int i = tid; i < 32 * KW; i += 128) sw[i] = wc[cg * 32 * KW + i];

    {
        const int row = tid >> 2;
        const int l4  = tid & 3;
        const float* qrow = qb + (size_t)row * LL + l0 - 8;
        for (int j = l4; j < 34; j += 4) {
            int idx = j * 4;
            float4 v;
            if (l0 - 8 + idx >= 0) v = *(const float4*)(qrow + idx);
            else v = make_float4(0.f, 0.f, 0.f, 0.f);
            *(float4*)&sq[row][idx] = v;
        }
    }
    __syncthreads();

    const int li = tid;
    float acc = 0.f;
#pragma unroll
    for (int cp = 0; cp < 32; ++cp) {
        const float* r  = &sq[cp][li + 4];
        const float* wr = &sw[cp * KW];
        acc = fmaf(wr[0], r[0], acc);
        acc = fmaf(wr[1], r[1], acc);
        acc = fmaf(wr[2], r[2], acc);
        acc = fmaf(wr[3], r[3], acc);
        acc = fmaf(wr[4], r[4], acc);
    }
    part[((size_t)cg * BGN + bg) * LL + l0 + li] = acc;
}

// ---------------------------------------------------------------------------
// Offsets stage 2: combine partials, bias/padding cases, tanh -> iy
// ---------------------------------------------------------------------------
__global__ __launch_bounds__(256) void offsets_finish_kernel(
    const float* __restrict__ part, const float* __restrict__ wc,
    float* __restrict__ offv)
{
    int i = blockIdx.x * 256 + threadIdx.x;    // over BGN*LL
    int bg = i >> 12;
    int l  = i & (LL - 1);
    float acc;
    if (l < 2) {
        acc = wc[GCC * KW + 1];                 // conv1 zero-padding region
    } else {
        acc = wc[GCC * KW]
            + part[((size_t)0 * BGN + bg) * LL + l]
            + part[((size_t)1 * BGN + bg) * LL + l]
            + part[((size_t)2 * BGN + bg) * LL + l]
            + part[((size_t)3 * BGN + bg) * LL + l];
    }
    float off = tanhf(acc) * (float)KW;
    float vg  = (float)l + off;
    float iy  = vg * ((float)LL / (float)(LL + 2 * (KW / 2) - 1)) - 0.5f;
    offv[(size_t)bg * LL + l] = iy;
}

// ---------------------------------------------------------------------------
// Bilinear gather -> xs in [B, L, C] layout, written as bf16 hi/lo pair
// ---------------------------------------------------------------------------
__global__ __launch_bounds__(256) void gather_kernel(
    const float* __restrict__ x, const float* __restrict__ offv,
    unsigned short* __restrict__ xshi, unsigned short* __restrict__ xslo)
{
    int bg = blockIdx.y;
    int b = bg >> 2, g = bg & 3;
    int l  = blockIdx.x * 8 + (threadIdx.x >> 5);
    int d4 = (threadIdx.x & 31) * 4;

    float iy = offv[(size_t)bg * LL + l];
    float fi = floorf(iy);
    float w1 = iy - fi;
    int i0 = (int)fi;
    int i1 = i0 + 1;

    const float* xb = x + (size_t)b * LL * CC + (size_t)g * GCC + d4;
    float4 v0 = make_float4(0.f, 0.f, 0.f, 0.f);
    float4 v1 = make_float4(0.f, 0.f, 0.f, 0.f);
    if (i0 >= 0 && i0 < LL) v0 = *(const float4*)(xb + (size_t)i0 * CC);
    if (i1 >= 0 && i1 < LL) v1 = *(const float4*)(xb + (size_t)i1 * CC);
    float w0 = 1.f - w1;
    float4 r = make_float4(v0.x * w0 + v1.x * w1, v0.y * w0 + v1.y * w1,
                           v0.z * w0 + v1.z * w1, v0.w * w0 + v1.w * w1);
    size_t o = ((size_t)b * LL + l) * CC + (size_t)g * GCC + d4;
    ushort4 h, lo4;
    split2(r.x, h.x, lo4.x); split2(r.y, h.y, lo4.y);
    split2(r.z, h.z, lo4.z); split2(r.w, h.w, lo4.w);
    *(ushort4*)(xshi + o) = h;
    *(ushort4*)(xslo + o) = lo4;
}

// ---------------------------------------------------------------------------
// Attention logits, split-K (fp32 vector; small op)
// ---------------------------------------------------------------------------
__global__ __launch_bounds__(64) void qk_logits(
    const float* __restrict__ q, const float* __restrict__ k,
    float* __restrict__ part)
{
    int ks = blockIdx.x, bh = blockIdx.y;
    int b = bh >> 4, h = bh & 15;
    int lane = threadIdx.x;
    int ti = lane >> 3, tj = lane & 7;
    const float* qb = q + ((size_t)b * CC + h * HCC + ti * 4) * LL;
    const float* kb = k + ((size_t)b * CC + h * HCC + tj * 4) * LL;

    float acc[4][4];
#pragma unroll
    for (int i = 0; i < 4; ++i)
#pragma unroll
        for (int j = 0; j < 4; ++j) acc[i][j] = 0.f;

    const int chunk = LL / KSPLIT;
    int l0 = ks * chunk;
    for (int l = l0; l < l0 + chunk; l += 8) {
        float4 qa[4][2], kv[4][2];
#pragma unroll
        for (int p = 0; p < 4; ++p) {
            qa[p][0] = *(const float4*)(qb + (size_t)p * LL + l);
            qa[p][1] = *(const float4*)(qb + (size_t)p * LL + l + 4);
            kv[p][0] = *(const float4*)(kb + (size_t)p * LL + l);
            kv[p][1] = *(const float4*)(kb + (size_t)p * LL + l + 4);
        }
#pragma unroll
        for (int i = 0; i < 4; ++i)
#pragma unroll
            for (int j = 0; j < 4; ++j) {
                float s = acc[i][j];
                s = fmaf(qa[i][0].x, kv[j][0].x, s);
                s = fmaf(qa[i][0].y, kv[j][0].y, s);
                s = fmaf(qa[i][0].z, kv[j][0].z, s);
                s = fmaf(qa[i][0].w, kv[j][0].w, s);
                s = fmaf(qa[i][1].x, kv[j][1].x, s);
                s = fmaf(qa[i][1].y, kv[j][1].y, s);
                s = fmaf(qa[i][1].z, kv[j][1].z, s);
                s = fmaf(qa[i][1].w, kv[j][1].w, s);
                acc[i][j] = s;
            }
    }
#pragma unroll
    for (int i = 0; i < 4; ++i)
#pragma unroll
        for (int j = 0; j < 4; ++j)
            part[(((size_t)bh * KSPLIT + ks) * HCC + ti * 4 + i) * HCC + tj * 4 + j] = acc[i][j];
}

__global__ __launch_bounds__(64) void softmax_kernel(
    const float* __restrict__ part, float* __restrict__ attn)
{
    int bh = blockIdx.x;
    int i = threadIdx.x;
    if (i >= HCC) return;
    const float SCALE = 0.044194173824159216f;  // 512^-0.5

    float lg[HCC];
    float mx = -1e30f;
#pragma unroll
    for (int j = 0; j < HCC; ++j) {
        float s = 0.f;
        for (int ks = 0; ks < KSPLIT; ++ks)
            s += part[(((size_t)bh * KSPLIT + ks) * HCC + i) * HCC + j];
        s *= SCALE;
        lg[j] = s;
        mx = fmaxf(mx, s);
    }
    float sum = 0.f;
#pragma unroll
    for (int j = 0; j < HCC; ++j) {
        float e = expf(lg[j] - mx);
        lg[j] = e;
        sum += e;
    }
    float inv = 1.f / sum;
#pragma unroll
    for (int j = 0; j < HCC; ++j)
        attn[((size_t)bh * HCC + i) * HCC + j] = lg[j] * inv;
}

// ---------------------------------------------------------------------------
// o[bh,i,l] = sum_j attn[i,j]*v[bh,j,l], -> final [B,L,C] layout as bf16 pair
// ---------------------------------------------------------------------------
__global__ __launch_bounds__(256) void attn_v_kernel(
    const float* __restrict__ attn, const float* __restrict__ v,
    unsigned short* __restrict__ ohi, unsigned short* __restrict__ olo)
{
    int bh = blockIdx.y;
    int b = bh >> 4, h = bh & 15;
    int tid = threadIdx.x;
    int i = tid >> 3, lsub = tid & 7;

    float arow[HCC];
#pragma unroll
    for (int j = 0; j < HCC; ++j)
        arow[j] = attn[((size_t)bh * HCC + i) * HCC + j];

    const float* vb = v + ((size_t)b * CC + h * HCC) * LL;
    __shared__ float os[HCC][65];

    for (int l0 = blockIdx.x * 512; l0 < blockIdx.x * 512 + 512; l0 += 64) {
        int lbase = l0 + lsub * 8;
        float4 a0 = make_float4(0.f, 0.f, 0.f, 0.f);
        float4 a1 = make_float4(0.f, 0.f, 0.f, 0.f);
#pragma unroll 8
        for (int j = 0; j < HCC; ++j) {
            float aw = arow[j];
            float4 v0 = *(const float4*)(vb + (size_t)j * LL + lbase);
            float4 v1 = *(const float4*)(vb + (size_t)j * LL + lbase + 4);
            a0.x = fmaf(aw, v0.x, a0.x); a0.y = fmaf(aw, v0.y, a0.y);
            a0.z = fmaf(aw, v0.z, a0.z); a0.w = fmaf(aw, v0.w, a0.w);
            a1.x = fmaf(aw, v1.x, a1.x); a1.y = fmaf(aw, v1.y, a1.y);
            a1.z = fmaf(aw, v1.z, a1.z); a1.w = fmaf(aw, v1.w, a1.w);
        }
        os[i][lsub*8+0] = a0.x; os[i][lsub*8+1] = a0.y;
        os[i][lsub*8+2] = a0.z; os[i][lsub*8+3] = a0.w;
        os[i][lsub*8+4] = a1.x; os[i][lsub*8+5] = a1.y;
        os[i][lsub*8+6] = a1.z; os[i][lsub*8+7] = a1.w;
        __syncthreads();
        int i2 = tid & 31, lw = tid >> 5;
#pragma unroll
        for (int c = 0; c < 8; ++c) {
            int ll = lw * 8 + c;
            float val = os[i2][ll];
            unsigned short hbits, lbits;
            split2(val, hbits, lbits);
            size_t oidx = ((size_t)b * LL + l0 + ll) * CC + h * HCC + i2;
            ohi[oidx] = hbits;
            olo[oidx] = lbits;
        }
        __syncthreads();
    }
}

// ---------------------------------------------------------------------------
extern "C" void kernel_launch(void* const* d_in, const int* in_sizes, int n_in,
                              void* d_out, int out_size, void* d_ws, size_t ws_size,
                              hipStream_t stream)
{
    (void)in_sizes; (void)n_in; (void)out_size; (void)ws_size;
    const float* x     = (const float*)d_in[0];
    const float* Wq    = (const float*)d_in[1];
    const float* bq    = (const float*)d_in[2];
    const float* Wk    = (const float*)d_in[3];
    const float* bk    = (const float*)d_in[4];
    const float* Wv    = (const float*)d_in[5];
    const float* bv    = (const float*)d_in[6];
    const float* Woff1 = (const float*)d_in[7];
    const float* boff1 = (const float*)d_in[8];
    const float* Woff2 = (const float*)d_in[9];
    const float* boff2 = (const float*)d_in[10];
    const float* rpb   = (const float*)d_in[11];
    const float* Wout  = (const float*)d_in[12];
    const float* bout  = (const float*)d_in[13];
    float* out = (float*)d_out;

    float* ws = (float*)d_ws;
    float* q    = ws;                          // [B,C,L]  8,388,608 f
    float* kbuf = ws + 8388608;                // [B,C,L]  8,388,608 f
    float* vbuf = ws + 16777216;               // [B,C,L]  8,388,608 f
    unsigned short* dhi = (unsigned short*)(ws + 25165824);   // 8,388,608 u16
    unsigned short* dlo = (unsigned short*)(ws + 25165824 + 4194304);
    unsigned short* whi = (unsigned short*)(ws + 33554432);   // 4x262144 u16
    unsigned short* wlo = (unsigned short*)(ws + 33554432 + 524288);
    float* offv = ws + 34603008;               // [BG,L]  65,536
    float* wcmb = ws + 34668544;               // 1,024
    float* part = ws + 34669568;               // [64,16,32,32] 1,048,576 (also offsets partials)
    float* attn = ws + 35718144;               // [64,32,32] 65,536

    const size_t NK = (size_t)LL * CC;   // per-batch activation elems

    comb_weights<<<dim3(3), dim3(256), 0, stream>>>(Woff1, boff1, Woff2, boff2, wcmb);
    split_w_kernel<<<dim3(256, 4), dim3(256), 0, stream>>>(Wq, Wk, Wv, Wout, whi, wlo);
    split_x_kernel<<<dim3(8192), dim3(256), 0, stream>>>(x, dhi, dlo, 2097152);

    // q = Wq @ x^T -> [B,C,L]
    gemm_split_mfma<<<dim3(32, 4, 4), dim3(256), 0, stream>>>(
        whi + 0 * 262144, wlo + 0 * 262144, dhi, dlo, bq, nullptr,
        q, CC, LL, CC, 0, NK, 0);

    // offset prediction (two-stage, parallel)
    offsets_part_kernel<<<dim3(32, 16, 4), dim3(128), 0, stream>>>(q, wcmb, part);
    offsets_finish_kernel<<<dim3(256), dim3(256), 0, stream>>>(part, wcmb, offv);
    gather_kernel<<<dim3(512, 16), dim3(256), 0, stream>>>(x, offv, dhi, dlo);

    // k = Wk @ xs^T ; v = Wv @ xs^T + rpb
    gemm_split_mfma<<<dim3(32, 4, 4), dim3(256), 0, stream>>>(
        whi + 1 * 262144, wlo + 1 * 262144, dhi, dlo, bk, nullptr,
        kbuf, CC, LL, CC, 0, NK, 0);
    gemm_split_mfma<<<dim3(32, 4, 4), dim3(256), 0, stream>>>(
        whi + 2 * 262144, wlo + 2 * 262144, dhi, dlo, bv, rpb,
        vbuf, CC, LL, CC, 0, NK, 0);

    qk_logits<<<dim3(KSPLIT, BHN), dim3(64), 0, stream>>>(q, kbuf, part);
    softmax_kernel<<<dim3(BHN), dim3(64), 0, stream>>>(part, attn);
    attn_v_kernel<<<dim3(8, BHN), dim3(256), 0, stream>>>(attn, vbuf, dhi, dlo);

    // out = o @ Wout^T + bout -> [B,L,C]
    gemm_split_mfma<<<dim3(4, 32, 4), dim3(256), 0, stream>>>(
        dhi, dlo, whi + 3 * 262144, wlo + 3 * 262144, bout, nullptr,
        out, LL, CC, CC, NK, 0, 1);
}

// Round 9
// 401.412 us; speedup vs baseline: 1.0073x; 1.0073x over previous
//
#include <hip/hip_runtime.h>
#include <math.h>

// Problem constants
#define BB   4
#define LL   4096
#define CC   512
#define GG   4
#define HH   16
#define KW   5      // conv kernel / offset range factor
#define GCC  128    // C / G
#define HCC  32     // C / H
#define BGN  (BB*GG)   // 16
#define BHN  (BB*HH)   // 64
#define KSPLIT 16

typedef __attribute__((ext_vector_type(8))) __bf16 bf16x8;
typedef __attribute__((ext_vector_type(4))) float f32x4;

// ---------------------------------------------------------------------------
// bf16 split helpers (manual RNE, no header-struct dependence)
// ---------------------------------------------------------------------------
__device__ __forceinline__ unsigned int f2bf_bits(float f) {
    unsigned int u = __float_as_uint(f);
    return (u + 0x7FFFu + ((u >> 16) & 1u)) >> 16;
}
__device__ __forceinline__ float bfbits2f(unsigned int s) {
    return __uint_as_float(s << 16);
}
__device__ __forceinline__ void split2(float v, unsigned short& h, unsigned short& l) {
    unsigned int hb = f2bf_bits(v);
    float hf = bfbits2f(hb);
    unsigned int lb = f2bf_bits(v - hf);
    h = (unsigned short)hb; l = (unsigned short)lb;
}

__device__ __forceinline__ void gload16(const void* g, void* l) {
    __builtin_amdgcn_global_load_lds(
        (const __attribute__((address_space(1))) void*)g,
        (__attribute__((address_space(3))) void*)l, 16, 0, 0);
}

// ---------------------------------------------------------------------------
// split fp32 -> (bf16 hi, bf16 lo), vectorized x4
// ---------------------------------------------------------------------------
__global__ __launch_bounds__(256) void split_x_kernel(
    const float* __restrict__ in, unsigned short* __restrict__ hi,
    unsigned short* __restrict__ lo, int n4)
{
    int i = blockIdx.x * 256 + threadIdx.x;
    if (i >= n4) return;
    float4 v = ((const float4*)in)[i];
    ushort4 h, l;
    split2(v.x, h.x, l.x); split2(v.y, h.y, l.y);
    split2(v.z, h.z, l.z); split2(v.w, h.w, l.w);
    ((ushort4*)hi)[i] = h;
    ((ushort4*)lo)[i] = l;
}

// 4 weight matrices [512x512] each -> hi/lo segments of 262144 elements
__global__ __launch_bounds__(256) void split_w_kernel(
    const float* __restrict__ W0, const float* __restrict__ W1,
    const float* __restrict__ W2, const float* __restrict__ W3,
    unsigned short* __restrict__ hi, unsigned short* __restrict__ lo)
{
    int w = blockIdx.y;
    const float* W = (w == 0) ? W0 : (w == 1) ? W1 : (w == 2) ? W2 : W3;
    size_t seg4 = (size_t)w * 65536;   // 262144/4
    int i = blockIdx.x * 256 + threadIdx.x;   // x4 elements
    float4 v = ((const float4*)W)[i];
    ushort4 h, l;
    split2(v.x, h.x, l.x); split2(v.y, h.y, l.y);
    split2(v.z, h.z, l.z); split2(v.w, h.w, l.w);
    ((ushort4*)hi)[seg4 + i] = h;
    ((ushort4*)lo)[seg4 + i] = l;
}

// ---------------------------------------------------------------------------
// Split-bf16 MFMA GEMM:  D[b][r][c] = sum_k A[b?][r,k]*B[b?][c,k]
// 128x128 tile, BK=32, 256 thr (4 waves 2x2, each 64x64 = 4x4 frags 16x16).
// 3 MFMAs per (fi,fj) k-step: hi*hi + lo*hi + hi*lo.
// Single-buffer 32 KB LDS (grid-bound residency: 32 KB lets 4 blocks/CU when
// grid >= 1024) + XOR chunk swizzle (verified: bank conflicts 2.1M -> 0).
// DUAL-SET support: blockIdx.y >= ySplit selects the second A/bias/out set
// (k+v GEMMs merged into one 1024-block dispatch -> 4 blocks/CU residency;
// round-8 theory: the GEMMs are grid/latency-bound at 2 blocks/CU).
// rpb applies to the second set only.
// ---------------------------------------------------------------------------
__global__ __launch_bounds__(256) void gemm_split_mfma(
    const unsigned short* __restrict__ Ahi, const unsigned short* __restrict__ Alo,
    const unsigned short* __restrict__ Ahi2, const unsigned short* __restrict__ Alo2,
    const unsigned short* __restrict__ Bhi, const unsigned short* __restrict__ Blo,
    const float* __restrict__ bias, const float* __restrict__ bias2,
    const float* __restrict__ rpb,
    float* __restrict__ out, float* __restrict__ out2, int ySplit,
    int RA, int RB, int Kd, size_t aStride, size_t bStride, int biasOnCol)
{
    __shared__ unsigned short sm[4][4096];   // [Ah,Al,Bh,Bl][128*32] = 32 KB

    const int b  = blockIdx.z;
    const int c0 = blockIdx.x * 128;

    // set selection (wave-uniform)
    int rblk = blockIdx.y;
    const unsigned short* Ah_ = Ahi;
    const unsigned short* Al_ = Alo;
    const float* bias_ = bias;
    const float* rpb_  = nullptr;
    float* out_ = out;
    if (rblk >= ySplit) {
        rblk -= ySplit;
        Ah_ = Ahi2; Al_ = Alo2; bias_ = bias2; out_ = out2; rpb_ = rpb;
    }
    const int r0 = rblk * 128;

    const int tid  = threadIdx.x;
    const int lane = tid & 63;
    const int wv   = tid >> 6;
    const int wr   = wv >> 1, wc = wv & 1;

    // staging: wave wv covers tile rows [wv*32, wv*32+32); 2 instr/matrix.
    // source chunk pre-swizzled: schunk = c ^ ((srow>>1)&3)
    const int srow   = lane >> 2;
    const int schunk = (lane & 3) ^ ((lane >> 3) & 3);
    const size_t laneA = (size_t)(r0 + wv * 32 + srow) * Kd + (size_t)(schunk * 8);
    const size_t laneB = (size_t)(c0 + wv * 32 + srow) * Kd + (size_t)(schunk * 8);
    const unsigned short* gAh = Ah_ + (size_t)b * aStride + laneA;
    const unsigned short* gAl = Al_ + (size_t)b * aStride + laneA;
    const unsigned short* gBh = Bhi + (size_t)b * bStride + laneB;
    const unsigned short* gBl = Blo + (size_t)b * bStride + laneB;
    const size_t rowskip = (size_t)16 * Kd;
    const int ldsOff = wv * 1024;               // 32 rows * 32 u16

    // fragment read: slot = kblk ^ ((row>>1)&3); row-dependent part reduces
    // to (lane>>1)&3 for all fi (wr*64, fi*16 are 0 mod 8).
    const int lr = lane & 15;
    const int kx = ((lane >> 4) ^ ((lane >> 1) & 3)) * 8;
    const int aOff = (wr * 64 + lr) * 32 + kx;
    const int bOff = (wc * 64 + lr) * 32 + kx;

    f32x4 acc[4][4];
#pragma unroll
    for (int i = 0; i < 4; ++i)
#pragma unroll
        for (int j = 0; j < 4; ++j) acc[i][j] = (f32x4){0.f, 0.f, 0.f, 0.f};

    bf16x8 ah[4], al[4], bh[4], bl[4];

    for (int k0 = 0; k0 < Kd; k0 += 32) {
        // stage current tile
        gload16(gAh + k0, &sm[0][ldsOff]);
        gload16(gAh + k0 + rowskip, &sm[0][ldsOff + 512]);
        gload16(gAl + k0, &sm[1][ldsOff]);
        gload16(gAl + k0 + rowskip, &sm[1][ldsOff + 512]);
        gload16(gBh + k0, &sm[2][ldsOff]);
        gload16(gBh + k0 + rowskip, &sm[2][ldsOff + 512]);
        gload16(gBl + k0, &sm[3][ldsOff]);
        gload16(gBl + k0 + rowskip, &sm[3][ldsOff + 512]);
        __syncthreads();   // drains vmcnt -> tile resident

        const unsigned short* mAh = &sm[0][aOff];
        const unsigned short* mAl = &sm[1][aOff];
        const unsigned short* mBh = &sm[2][bOff];
        const unsigned short* mBl = &sm[3][bOff];
#pragma unroll
        for (int i = 0; i < 4; ++i) {
            ah[i] = *(const bf16x8*)(mAh + i * 512);
            al[i] = *(const bf16x8*)(mAl + i * 512);
        }
#pragma unroll
        for (int j = 0; j < 4; ++j) {
            bh[j] = *(const bf16x8*)(mBh + j * 512);
            bl[j] = *(const bf16x8*)(mBl + j * 512);
        }
#pragma unroll
        for (int i = 0; i < 4; ++i)
#pragma unroll
            for (int j = 0; j < 4; ++j) {
                acc[i][j] = __builtin_amdgcn_mfma_f32_16x16x32_bf16(ah[i], bh[j], acc[i][j], 0, 0, 0);
                acc[i][j] = __builtin_amdgcn_mfma_f32_16x16x32_bf16(al[i], bh[j], acc[i][j], 0, 0, 0);
                acc[i][j] = __builtin_amdgcn_mfma_f32_16x16x32_bf16(ah[i], bl[j], acc[i][j], 0, 0, 0);
            }
        __syncthreads();   // all waves done reading before next stage
    }

    // epilogue: C/D layout col=lane&15, row=(lane>>4)*4+reg  [m89 verified]
    const int lg4 = (lane >> 4) * 4;
    float bcol[4];
#pragma unroll
    for (int fj = 0; fj < 4; ++fj)
        bcol[fj] = biasOnCol ? bias_[c0 + wc * 64 + fj * 16 + lr] : 0.f;

#pragma unroll
    for (int fi = 0; fi < 4; ++fi) {
#pragma unroll
        for (int reg = 0; reg < 4; ++reg) {
            const int r = r0 + wr * 64 + fi * 16 + lg4 + reg;
            const float br = biasOnCol ? 0.f : bias_[r];
            float* orow = out_ + ((size_t)b * RA + r) * RB + c0;
            const float* prow = rpb_ ? (rpb_ + (size_t)r * RB + c0) : nullptr;
#pragma unroll
            for (int fj = 0; fj < 4; ++fj) {
                const int c = wc * 64 + fj * 16 + lr;
                float val = acc[fi][fj][reg] + br + bcol[fj];
                if (prow) val += prow[c];
                orow[c] = val;
            }
        }
    }
}

// ---------------------------------------------------------------------------
// Fuse the two offset convs (linear, no activation between)
// ---------------------------------------------------------------------------
__global__ void comb_weights(const float* __restrict__ Woff1, const float* __restrict__ boff1,
                             const float* __restrict__ Woff2, const float* __restrict__ boff2,
                             float* __restrict__ wc)
{
    int idx = blockIdx.x * 256 + threadIdx.x;
    if (idx < GCC * KW) {
        int cp = idx / KW, t = idx - cp * KW;
        float s = 0.f;
        for (int c = 0; c < GCC; ++c)
            s = fmaf(Woff2[c], Woff1[((size_t)c * GCC + cp) * KW + t], s);
        wc[idx] = s;
    } else if (idx == GCC * KW) {
        float s = boff2[0];
        for (int c = 0; c < GCC; ++c) s = fmaf(Woff2[c], boff1[c], s);
        wc[idx] = s;
    } else if (idx == GCC * KW + 1) {
        wc[idx] = boff2[0];
    }
}

// ---------------------------------------------------------------------------
// Offsets stage 1: channel-split conv partials.
// ---------------------------------------------------------------------------
#define OLT 128
__global__ __launch_bounds__(128) void offsets_part_kernel(
    const float* __restrict__ q, const float* __restrict__ wc,
    float* __restrict__ part)
{
    __shared__ float sq[32][140];   // cols 0..135 used; pos = l0-8+col
    __shared__ float sw[32 * KW];

    const int l0 = blockIdx.x * OLT;
    const int bg = blockIdx.y;
    const int cg = blockIdx.z;
    const int tid = threadIdx.x;

    const float* qb = q + ((size_t)bg * GCC + cg * 32) * LL;

    for (int i = tid; i < 32 * KW; i += 128) sw[i] = wc[cg * 32 * KW + i];

    {
        const int row = tid >> 2;
        const int l4  = tid & 3;
        const float* qrow = qb + (size_t)row * LL + l0 - 8;
        for (int j = l4; j < 34; j += 4) {
            int idx = j * 4;
            float4 v;
            if (l0 - 8 + idx >= 0) v = *(const float4*)(qrow + idx);
            else v = make_float4(0.f, 0.f, 0.f, 0.f);
            *(float4*)&sq[row][idx] = v;
        }
    }
    __syncthreads();

    const int li = tid;
    float acc = 0.f;
#pragma unroll
    for (int cp = 0; cp < 32; ++cp) {
        const float* r  = &sq[cp][li + 4];
        const float* wr = &sw[cp * KW];
        acc = fmaf(wr[0], r[0], acc);
        acc = fmaf(wr[1], r[1], acc);
        acc = fmaf(wr[2], r[2], acc);
        acc = fmaf(wr[3], r[3], acc);
        acc = fmaf(wr[4], r[4], acc);
    }
    part[((size_t)cg * BGN + bg) * LL + l0 + li] = acc;
}

// ---------------------------------------------------------------------------
// Offsets stage 2: combine partials, bias/padding cases, tanh -> iy
// ---------------------------------------------------------------------------
__global__ __launch_bounds__(256) void offsets_finish_kernel(
    const float* __restrict__ part, const float* __restrict__ wc,
    float* __restrict__ offv)
{
    int i = blockIdx.x * 256 + threadIdx.x;    // over BGN*LL
    int bg = i >> 12;
    int l  = i & (LL - 1);
    float acc;
    if (l < 2) {
        acc = wc[GCC * KW + 1];                 // conv1 zero-padding region
    } else {
        acc = wc[GCC * KW]
            + part[((size_t)0 * BGN + bg) * LL + l]
            + part[((size_t)1 * BGN + bg) * LL + l]
            + part[((size_t)2 * BGN + bg) * LL + l]
            + part[((size_t)3 * BGN + bg) * LL + l];
    }
    float off = tanhf(acc) * (float)KW;
    float vg  = (float)l + off;
    float iy  = vg * ((float)LL / (float)(LL + 2 * (KW / 2) - 1)) - 0.5f;
    offv[(size_t)bg * LL + l] = iy;
}

// ---------------------------------------------------------------------------
// Bilinear gather -> xs in [B, L, C] layout, written as bf16 hi/lo pair
// ---------------------------------------------------------------------------
__global__ __launch_bounds__(256) void gather_kernel(
    const float* __restrict__ x, const float* __restrict__ offv,
    unsigned short* __restrict__ xshi, unsigned short* __restrict__ xslo)
{
    int bg = blockIdx.y;
    int b = bg >> 2, g = bg & 3;
    int l  = blockIdx.x * 8 + (threadIdx.x >> 5);
    int d4 = (threadIdx.x & 31) * 4;

    float iy = offv[(size_t)bg * LL + l];
    float fi = floorf(iy);
    float w1 = iy - fi;
    int i0 = (int)fi;
    int i1 = i0 + 1;

    const float* xb = x + (size_t)b * LL * CC + (size_t)g * GCC + d4;
    float4 v0 = make_float4(0.f, 0.f, 0.f, 0.f);
    float4 v1 = make_float4(0.f, 0.f, 0.f, 0.f);
    if (i0 >= 0 && i0 < LL) v0 = *(const float4*)(xb + (size_t)i0 * CC);
    if (i1 >= 0 && i1 < LL) v1 = *(const float4*)(xb + (size_t)i1 * CC);
    float w0 = 1.f - w1;
    float4 r = make_float4(v0.x * w0 + v1.x * w1, v0.y * w0 + v1.y * w1,
                           v0.z * w0 + v1.z * w1, v0.w * w0 + v1.w * w1);
    size_t o = ((size_t)b * LL + l) * CC + (size_t)g * GCC + d4;
    ushort4 h, lo4;
    split2(r.x, h.x, lo4.x); split2(r.y, h.y, lo4.y);
    split2(r.z, h.z, lo4.z); split2(r.w, h.w, lo4.w);
    *(ushort4*)(xshi + o) = h;
    *(ushort4*)(xslo + o) = lo4;
}

// ---------------------------------------------------------------------------
// Attention logits, split-K (fp32 vector; small op)
// ---------------------------------------------------------------------------
__global__ __launch_bounds__(64) void qk_logits(
    const float* __restrict__ q, const float* __restrict__ k,
    float* __restrict__ part)
{
    int ks = blockIdx.x, bh = blockIdx.y;
    int b = bh >> 4, h = bh & 15;
    int lane = threadIdx.x;
    int ti = lane >> 3, tj = lane & 7;
    const float* qb = q + ((size_t)b * CC + h * HCC + ti * 4) * LL;
    const float* kb = k + ((size_t)b * CC + h * HCC + tj * 4) * LL;

    float acc[4][4];
#pragma unroll
    for (int i = 0; i < 4; ++i)
#pragma unroll
        for (int j = 0; j < 4; ++j) acc[i][j] = 0.f;

    const int chunk = LL / KSPLIT;
    int l0 = ks * chunk;
    for (int l = l0; l < l0 + chunk; l += 8) {
        float4 qa[4][2], kv[4][2];
#pragma unroll
        for (int p = 0; p < 4; ++p) {
            qa[p][0] = *(const float4*)(qb + (size_t)p * LL + l);
            qa[p][1] = *(const float4*)(qb + (size_t)p * LL + l + 4);
            kv[p][0] = *(const float4*)(kb + (size_t)p * LL + l);
            kv[p][1] = *(const float4*)(kb + (size_t)p * LL + l + 4);
        }
#pragma unroll
        for (int i = 0; i < 4; ++i)
#pragma unroll
            for (int j = 0; j < 4; ++j) {
                float s = acc[i][j];
                s = fmaf(qa[i][0].x, kv[j][0].x, s);
                s = fmaf(qa[i][0].y, kv[j][0].y, s);
                s = fmaf(qa[i][0].z, kv[j][0].z, s);
                s = fmaf(qa[i][0].w, kv[j][0].w, s);
                s = fmaf(qa[i][1].x, kv[j][1].x, s);
                s = fmaf(qa[i][1].y, kv[j][1].y, s);
                s = fmaf(qa[i][1].z, kv[j][1].z, s);
                s = fmaf(qa[i][1].w, kv[j][1].w, s);
                acc[i][j] = s;
            }
    }
#pragma unroll
    for (int i = 0; i < 4; ++i)
#pragma unroll
        for (int j = 0; j < 4; ++j)
            part[(((size_t)bh * KSPLIT + ks) * HCC + ti * 4 + i) * HCC + tj * 4 + j] = acc[i][j];
}

__global__ __launch_bounds__(64) void softmax_kernel(
    const float* __restrict__ part, float* __restrict__ attn)
{
    int bh = blockIdx.x;
    int i = threadIdx.x;
    if (i >= HCC) return;
    const float SCALE = 0.044194173824159216f;  // 512^-0.5

    float lg[HCC];
    float mx = -1e30f;
#pragma unroll
    for (int j = 0; j < HCC; ++j) {
        float s = 0.f;
        for (int ks = 0; ks < KSPLIT; ++ks)
            s += part[(((size_t)bh * KSPLIT + ks) * HCC + i) * HCC + j];
        s *= SCALE;
        lg[j] = s;
        mx = fmaxf(mx, s);
    }
    float sum = 0.f;
#pragma unroll
    for (int j = 0; j < HCC; ++j) {
        float e = expf(lg[j] - mx);
        lg[j] = e;
        sum += e;
    }
    float inv = 1.f / sum;
#pragma unroll
    for (int j = 0; j < HCC; ++j)
        attn[((size_t)bh * HCC + i) * HCC + j] = lg[j] * inv;
}

// ---------------------------------------------------------------------------
// o[bh,i,l] = sum_j attn[i,j]*v[bh,j,l], -> final [B,L,C] layout as bf16 pair
// ---------------------------------------------------------------------------
__global__ __launch_bounds__(256) void attn_v_kernel(
    const float* __restrict__ attn, const float* __restrict__ v,
    unsigned short* __restrict__ ohi, unsigned short* __restrict__ olo)
{
    int bh = blockIdx.y;
    int b = bh >> 4, h = bh & 15;
    int tid = threadIdx.x;
    int i = tid >> 3, lsub = tid & 7;

    float arow[HCC];
#pragma unroll
    for (int j = 0; j < HCC; ++j)
        arow[j] = attn[((size_t)bh * HCC + i) * HCC + j];

    const float* vb = v + ((size_t)b * CC + h * HCC) * LL;
    __shared__ float os[HCC][65];

    for (int l0 = blockIdx.x * 512; l0 < blockIdx.x * 512 + 512; l0 += 64) {
        int lbase = l0 + lsub * 8;
        float4 a0 = make_float4(0.f, 0.f, 0.f, 0.f);
        float4 a1 = make_float4(0.f, 0.f, 0.f, 0.f);
#pragma unroll 8
        for (int j = 0; j < HCC; ++j) {
            float aw = arow[j];
            float4 v0 = *(const float4*)(vb + (size_t)j * LL + lbase);
            float4 v1 = *(const float4*)(vb + (size_t)j * LL + lbase + 4);
            a0.x = fmaf(aw, v0.x, a0.x); a0.y = fmaf(aw, v0.y, a0.y);
            a0.z = fmaf(aw, v0.z, a0.z); a0.w = fmaf(aw, v0.w, a0.w);
            a1.x = fmaf(aw, v1.x, a1.x); a1.y = fmaf(aw, v1.y, a1.y);
            a1.z = fmaf(aw, v1.z, a1.z); a1.w = fmaf(aw, v1.w, a1.w);
        }
        os[i][lsub*8+0] = a0.x; os[i][lsub*8+1] = a0.y;
        os[i][lsub*8+2] = a0.z; os[i][lsub*8+3] = a0.w;
        os[i][lsub*8+4] = a1.x; os[i][lsub*8+5] = a1.y;
        os[i][lsub*8+6] = a1.z; os[i][lsub*8+7] = a1.w;
        __syncthreads();
        int i2 = tid & 31, lw = tid >> 5;
#pragma unroll
        for (int c = 0; c < 8; ++c) {
            int ll = lw * 8 + c;
            float val = os[i2][ll];
            unsigned short hbits, lbits;
            split2(val, hbits, lbits);
            size_t oidx = ((size_t)b * LL + l0 + ll) * CC + h * HCC + i2;
            ohi[oidx] = hbits;
            olo[oidx] = lbits;
        }
        __syncthreads();
    }
}

// ---------------------------------------------------------------------------
extern "C" void kernel_launch(void* const* d_in, const int* in_sizes, int n_in,
                              void* d_out, int out_size, void* d_ws, size_t ws_size,
                              hipStream_t stream)
{
    (void)in_sizes; (void)n_in; (void)out_size; (void)ws_size;
    const float* x     = (const float*)d_in[0];
    const float* Wq    = (const float*)d_in[1];
    const float* bq    = (const float*)d_in[2];
    const float* Wk    = (const float*)d_in[3];
    const float* bk    = (const float*)d_in[4];
    const float* Wv    = (const float*)d_in[5];
    const float* bv    = (const float*)d_in[6];
    const float* Woff1 = (const float*)d_in[7];
    const float* boff1 = (const float*)d_in[8];
    const float* Woff2 = (const float*)d_in[9];
    const float* boff2 = (const float*)d_in[10];
    const float* rpb   = (const float*)d_in[11];
    const float* Wout  = (const float*)d_in[12];
    const float* bout  = (const float*)d_in[13];
    float* out = (float*)d_out;

    float* ws = (float*)d_ws;
    float* q    = ws;                          // [B,C,L]  8,388,608 f
    float* kbuf = ws + 8388608;                // [B,C,L]  8,388,608 f
    float* vbuf = ws + 16777216;               // [B,C,L]  8,388,608 f
    unsigned short* dhi = (unsigned short*)(ws + 25165824);   // 8,388,608 u16
    unsigned short* dlo = (unsigned short*)(ws + 25165824 + 4194304);
    unsigned short* whi = (unsigned short*)(ws + 33554432);   // 4x262144 u16
    unsigned short* wlo = (unsigned short*)(ws + 33554432 + 524288);
    float* offv = ws + 34603008;               // [BG,L]  65,536
    float* wcmb = ws + 34668544;               // 1,024
    float* part = ws + 34669568;               // [64,16,32,32] 1,048,576 (also offsets partials)
    float* attn = ws + 35718144;               // [64,32,32] 65,536

    const size_t NK = (size_t)LL * CC;   // per-batch activation elems
    const int NOSPLIT = 1 << 20;

    comb_weights<<<dim3(3), dim3(256), 0, stream>>>(Woff1, boff1, Woff2, boff2, wcmb);
    split_w_kernel<<<dim3(256, 4), dim3(256), 0, stream>>>(Wq, Wk, Wv, Wout, whi, wlo);
    split_x_kernel<<<dim3(8192), dim3(256), 0, stream>>>(x, dhi, dlo, 2097152);

    // q = Wq @ x^T -> [B,C,L]
    gemm_split_mfma<<<dim3(32, 4, 4), dim3(256), 0, stream>>>(
        whi + 0 * 262144, wlo + 0 * 262144, whi, wlo, dhi, dlo,
        bq, bq, nullptr, q, q, NOSPLIT,
        CC, LL, CC, 0, NK, 0);

    // offset prediction (two-stage, parallel)
    offsets_part_kernel<<<dim3(32, 16, 4), dim3(128), 0, stream>>>(q, wcmb, part);
    offsets_finish_kernel<<<dim3(256), dim3(256), 0, stream>>>(part, wcmb, offv);
    gather_kernel<<<dim3(512, 16), dim3(256), 0, stream>>>(x, offv, dhi, dlo);

    // k = Wk @ xs^T ; v = Wv @ xs^T + rpb  -- MERGED: 1024 blocks, set2 = v
    gemm_split_mfma<<<dim3(32, 8, 4), dim3(256), 0, stream>>>(
        whi + 1 * 262144, wlo + 1 * 262144,        // set1: Wk
        whi + 2 * 262144, wlo + 2 * 262144,        // set2: Wv
        dhi, dlo, bk, bv, rpb, kbuf, vbuf, 4,
        CC, LL, CC, 0, NK, 0);

    qk_logits<<<dim3(KSPLIT, BHN), dim3(64), 0, stream>>>(q, kbuf, part);
    softmax_kernel<<<dim3(BHN), dim3(64), 0, stream>>>(part, attn);
    attn_v_kernel<<<dim3(8, BHN), dim3(256), 0, stream>>>(attn, vbuf, dhi, dlo);

    // out = o @ Wout^T + bout -> [B,L,C]
    gemm_split_mfma<<<dim3(4, 32, 4), dim3(256), 0, stream>>>(
        dhi, dlo, dhi, dlo, whi + 3 * 262144, wlo + 3 * 262144,
        bout, bout, nullptr, out, out, NOSPLIT,
        LL, CC, CC, NK, 0, 1);
}

// Round 10
// 396.014 us; speedup vs baseline: 1.0210x; 1.0136x over previous
//
#include <hip/hip_runtime.h>
#include <math.h>

// Problem constants
#define BB   4
#define LL   4096
#define CC   512
#define GG   4
#define HH   16
#define KW   5      // conv kernel / offset range factor
#define GCC  128    // C / G
#define HCC  32     // C / H
#define BGN  (BB*GG)   // 16
#define BHN  (BB*HH)   // 64
#define KSPLIT 16

typedef __attribute__((ext_vector_type(8))) __bf16 bf16x8;
typedef __attribute__((ext_vector_type(4))) float f32x4;

// ---------------------------------------------------------------------------
// bf16 split helpers (manual RNE, no header-struct dependence)
// ---------------------------------------------------------------------------
__device__ __forceinline__ unsigned int f2bf_bits(float f) {
    unsigned int u = __float_as_uint(f);
    return (u + 0x7FFFu + ((u >> 16) & 1u)) >> 16;
}
__device__ __forceinline__ float bfbits2f(unsigned int s) {
    return __uint_as_float(s << 16);
}
__device__ __forceinline__ void split2(float v, unsigned short& h, unsigned short& l) {
    unsigned int hb = f2bf_bits(v);
    float hf = bfbits2f(hb);
    unsigned int lb = f2bf_bits(v - hf);
    h = (unsigned short)hb; l = (unsigned short)lb;
}

__device__ __forceinline__ void gload16(const void* g, void* l) {
    __builtin_amdgcn_global_load_lds(
        (const __attribute__((address_space(1))) void*)g,
        (__attribute__((address_space(3))) void*)l, 16, 0, 0);
}

// ---------------------------------------------------------------------------
// split fp32 -> (bf16 hi, bf16 lo), vectorized x4
// ---------------------------------------------------------------------------
__global__ __launch_bounds__(256) void split_x_kernel(
    const float* __restrict__ in, unsigned short* __restrict__ hi,
    unsigned short* __restrict__ lo, int n4)
{
    int i = blockIdx.x * 256 + threadIdx.x;
    if (i >= n4) return;
    float4 v = ((const float4*)in)[i];
    ushort4 h, l;
    split2(v.x, h.x, l.x); split2(v.y, h.y, l.y);
    split2(v.z, h.z, l.z); split2(v.w, h.w, l.w);
    ((ushort4*)hi)[i] = h;
    ((ushort4*)lo)[i] = l;
}

// 4 weight matrices [512x512] each -> hi/lo segments of 262144 elements
__global__ __launch_bounds__(256) void split_w_kernel(
    const float* __restrict__ W0, const float* __restrict__ W1,
    const float* __restrict__ W2, const float* __restrict__ W3,
    unsigned short* __restrict__ hi, unsigned short* __restrict__ lo)
{
    int w = blockIdx.y;
    const float* W = (w == 0) ? W0 : (w == 1) ? W1 : (w == 2) ? W2 : W3;
    size_t seg4 = (size_t)w * 65536;   // 262144/4
    int i = blockIdx.x * 256 + threadIdx.x;   // x4 elements
    float4 v = ((const float4*)W)[i];
    ushort4 h, l;
    split2(v.x, h.x, l.x); split2(v.y, h.y, l.y);
    split2(v.z, h.z, l.z); split2(v.w, h.w, l.w);
    ((ushort4*)hi)[seg4 + i] = h;
    ((ushort4*)lo)[seg4 + i] = l;
}

// ---------------------------------------------------------------------------
// Split-bf16 MFMA GEMM:  D[b][r][c] = sum_k A[b?][r,k]*B[b?][c,k]
// 128x128 tile, BK=32, 256 thr (4 waves 2x2, each 64x64 = 4x4 frags 16x16).
// 3 MFMAs per (fi,fj) k-step: hi*hi + lo*hi + hi*lo.
// Round-9: T4 counted-vmcnt 2-buffer pipeline. Prologue stages tiles 0,1
// (16 loads/wave in flight). Per step: vmcnt(8) waits ONLY the oldest tile
// (never drain-0 mid-loop) -> raw s_barrier -> ds_read frags -> lgkmcnt(0)
// + barrier (reads sampled before overwrite) -> STAGE tile t+2 into the
// just-read buffer -> MFMA with no memory waits. Staging latency spans ~2
// K-steps. XOR chunk swizzle kept (bank conflicts: verified 0).
// DUAL-SET: blockIdx.y >= ySplit selects second A/bias/out set (k+v merge).
// ---------------------------------------------------------------------------
__global__ __launch_bounds__(256) void gemm_split_mfma(
    const unsigned short* __restrict__ Ahi, const unsigned short* __restrict__ Alo,
    const unsigned short* __restrict__ Ahi2, const unsigned short* __restrict__ Alo2,
    const unsigned short* __restrict__ Bhi, const unsigned short* __restrict__ Blo,
    const float* __restrict__ bias, const float* __restrict__ bias2,
    const float* __restrict__ rpb,
    float* __restrict__ out, float* __restrict__ out2, int ySplit,
    int RA, int RB, int Kd, size_t aStride, size_t bStride, int biasOnCol)
{
    __shared__ unsigned short sm[2 * 4 * 4096];   // 2 bufs x [Ah,Al,Bh,Bl] x 8KB = 64 KB

    const int b  = blockIdx.z;
    const int c0 = blockIdx.x * 128;

    // set selection (block-uniform)
    int rblk = blockIdx.y;
    const unsigned short* Ah_ = Ahi;
    const unsigned short* Al_ = Alo;
    const float* bias_ = bias;
    const float* rpb_  = nullptr;
    float* out_ = out;
    if (rblk >= ySplit) {
        rblk -= ySplit;
        Ah_ = Ahi2; Al_ = Alo2; bias_ = bias2; out_ = out2; rpb_ = rpb;
    }
    const int r0 = rblk * 128;

    const int tid  = threadIdx.x;
    const int lane = tid & 63;
    const int wv   = tid >> 6;
    const int wr   = wv >> 1, wc = wv & 1;

    // staging: wave wv covers tile rows [wv*32, wv*32+32); 2 instr/matrix.
    // source chunk pre-swizzled: schunk = c ^ ((srow>>1)&3)
    const int srow   = lane >> 2;
    const int schunk = (lane & 3) ^ ((lane >> 3) & 3);
    const size_t laneA = (size_t)(r0 + wv * 32 + srow) * Kd + (size_t)(schunk * 8);
    const size_t laneB = (size_t)(c0 + wv * 32 + srow) * Kd + (size_t)(schunk * 8);
    const unsigned short* gAh = Ah_ + (size_t)b * aStride + laneA;
    const unsigned short* gAl = Al_ + (size_t)b * aStride + laneA;
    const unsigned short* gBh = Bhi + (size_t)b * bStride + laneB;
    const unsigned short* gBl = Blo + (size_t)b * bStride + laneB;
    const size_t rowskip = (size_t)16 * Kd;
    const int ldsOff = wv * 1024;               // 32 rows * 32 u16

    // fragment read: slot = kblk ^ ((row>>1)&3); row part reduces to (lane>>1)&3.
    const int lr = lane & 15;
    const int kx = ((lane >> 4) ^ ((lane >> 1) & 3)) * 8;
    const int aOff = (wr * 64 + lr) * 32 + kx;
    const int bOff = (wc * 64 + lr) * 32 + kx;

    f32x4 acc[4][4];
#pragma unroll
    for (int i = 0; i < 4; ++i)
#pragma unroll
        for (int j = 0; j < 4; ++j) acc[i][j] = (f32x4){0.f, 0.f, 0.f, 0.f};

    bf16x8 ah[4], al[4], bh[4], bl[4];

#define STAGE(bufbase, k0)                                                    \
    {                                                                         \
        unsigned short* d0 = &sm[(bufbase) + 0 * 4096 + ldsOff];              \
        gload16(gAh + (k0), d0);  gload16(gAh + (k0) + rowskip, d0 + 512);    \
        unsigned short* d1 = &sm[(bufbase) + 1 * 4096 + ldsOff];              \
        gload16(gAl + (k0), d1);  gload16(gAl + (k0) + rowskip, d1 + 512);    \
        unsigned short* d2 = &sm[(bufbase) + 2 * 4096 + ldsOff];              \
        gload16(gBh + (k0), d2);  gload16(gBh + (k0) + rowskip, d2 + 512);    \
        unsigned short* d3 = &sm[(bufbase) + 3 * 4096 + ldsOff];              \
        gload16(gBl + (k0), d3);  gload16(gBl + (k0) + rowskip, d3 + 512);    \
    }

#define LOADF(bufbase)                                                        \
    {                                                                         \
        const unsigned short* mAh = &sm[(bufbase) + 0 * 4096 + aOff];         \
        const unsigned short* mAl = &sm[(bufbase) + 1 * 4096 + aOff];         \
        const unsigned short* mBh = &sm[(bufbase) + 2 * 4096 + bOff];         \
        const unsigned short* mBl = &sm[(bufbase) + 3 * 4096 + bOff];         \
        _Pragma("unroll")                                                     \
        for (int i = 0; i < 4; ++i) {                                         \
            ah[i] = *(const bf16x8*)(mAh + i * 512);                          \
            al[i] = *(const bf16x8*)(mAl + i * 512);                          \
        }                                                                     \
        _Pragma("unroll")                                                     \
        for (int j = 0; j < 4; ++j) {                                         \
            bh[j] = *(const bf16x8*)(mBh + j * 512);                          \
            bl[j] = *(const bf16x8*)(mBl + j * 512);                          \
        }                                                                     \
    }

#define DOMFMA                                                                \
    {                                                                         \
        _Pragma("unroll")                                                     \
        for (int i = 0; i < 4; ++i)                                           \
            _Pragma("unroll")                                                 \
            for (int j = 0; j < 4; ++j) {                                     \
                acc[i][j] = __builtin_amdgcn_mfma_f32_16x16x32_bf16(ah[i], bh[j], acc[i][j], 0, 0, 0); \
                acc[i][j] = __builtin_amdgcn_mfma_f32_16x16x32_bf16(al[i], bh[j], acc[i][j], 0, 0, 0); \
                acc[i][j] = __builtin_amdgcn_mfma_f32_16x16x32_bf16(ah[i], bl[j], acc[i][j], 0, 0, 0); \
            }                                                                 \
    }

    const int nt = Kd >> 5;            // K-tiles (16 for K=512)
    // prologue: stage tiles 0 and 1 (16 loads/wave in flight)
    STAGE(0, 0)
    STAGE(16384, 32)

    int cur = 0;                       // buffer base of tile t: cur*16384
    for (int t = 0; t < nt; ++t) {
        const int bufb = cur ? 16384 : 0;
        // wait only the oldest tile's 8 loads (t+1 keeps flying); last: drain
        if (t < nt - 1) asm volatile("s_waitcnt vmcnt(8)" ::: "memory");
        else            asm volatile("s_waitcnt vmcnt(0)" ::: "memory");
        __builtin_amdgcn_s_barrier();          // all waves' tile-t loads landed
        LOADF(bufb)                            // ds_read tile t
        asm volatile("s_waitcnt lgkmcnt(0)" ::: "memory");  // reads sampled
        __builtin_amdgcn_sched_barrier(0);
        __builtin_amdgcn_s_barrier();          // everyone done reading buf t
        if (t + 2 < nt) STAGE(bufb, (t + 2) * 32)  // overwrite with tile t+2
        DOMFMA                                 // no memory waits here
        cur ^= 1;
    }

#undef STAGE
#undef LOADF
#undef DOMFMA

    // epilogue: C/D layout col=lane&15, row=(lane>>4)*4+reg  [m89 verified]
    const int lg4 = (lane >> 4) * 4;
    float bcol[4];
#pragma unroll
    for (int fj = 0; fj < 4; ++fj)
        bcol[fj] = biasOnCol ? bias_[c0 + wc * 64 + fj * 16 + lr] : 0.f;

#pragma unroll
    for (int fi = 0; fi < 4; ++fi) {
#pragma unroll
        for (int reg = 0; reg < 4; ++reg) {
            const int r = r0 + wr * 64 + fi * 16 + lg4 + reg;
            const float br = biasOnCol ? 0.f : bias_[r];
            float* orow = out_ + ((size_t)b * RA + r) * RB + c0;
            const float* prow = rpb_ ? (rpb_ + (size_t)r * RB + c0) : nullptr;
#pragma unroll
            for (int fj = 0; fj < 4; ++fj) {
                const int c = wc * 64 + fj * 16 + lr;
                float val = acc[fi][fj][reg] + br + bcol[fj];
                if (prow) val += prow[c];
                orow[c] = val;
            }
        }
    }
}

// ---------------------------------------------------------------------------
// Fuse the two offset convs (linear, no activation between)
// ---------------------------------------------------------------------------
__global__ void comb_weights(const float* __restrict__ Woff1, const float* __restrict__ boff1,
                             const float* __restrict__ Woff2, const float* __restrict__ boff2,
                             float* __restrict__ wc)
{
    int idx = blockIdx.x * 256 + threadIdx.x;
    if (idx < GCC * KW) {
        int cp = idx / KW, t = idx - cp * KW;
        float s = 0.f;
        for (int c = 0; c < GCC; ++c)
            s = fmaf(Woff2[c], Woff1[((size_t)c * GCC + cp) * KW + t], s);
        wc[idx] = s;
    } else if (idx == GCC * KW) {
        float s = boff2[0];
        for (int c = 0; c < GCC; ++c) s = fmaf(Woff2[c], boff1[c], s);
        wc[idx] = s;
    } else if (idx == GCC * KW + 1) {
        wc[idx] = boff2[0];
    }
}

// ---------------------------------------------------------------------------
// Offsets stage 1: channel-split conv partials.
// ---------------------------------------------------------------------------
#define OLT 128
__global__ __launch_bounds__(128) void offsets_part_kernel(
    const float* __restrict__ q, const float* __restrict__ wc,
    float* __restrict__ part)
{
    __shared__ float sq[32][140];   // cols 0..135 used; pos = l0-8+col
    __shared__ float sw[32 * KW];

    const int l0 = blockIdx.x * OLT;
    const int bg = blockIdx.y;
    const int cg = blockIdx.z;
    const int tid = threadIdx.x;

    const float* qb = q + ((size_t)bg * GCC + cg * 32) * LL;

    for (int i = tid; i < 32 * KW; i += 128) sw[i] = wc[cg * 32 * KW + i];

    {
        const int row = tid >> 2;
        const int l4  = tid & 3;
        const float* qrow = qb + (size_t)row * LL + l0 - 8;
        for (int j = l4; j < 34; j += 4) {
            int idx = j * 4;
            float4 v;
            if (l0 - 8 + idx >= 0) v = *(const float4*)(qrow + idx);
            else v = make_float4(0.f, 0.f, 0.f, 0.f);
            *(float4*)&sq[row][idx] = v;
        }
    }
    __syncthreads();

    const int li = tid;
    float acc = 0.f;
#pragma unroll
    for (int cp = 0; cp < 32; ++cp) {
        const float* r  = &sq[cp][li + 4];
        const float* wr = &sw[cp * KW];
        acc = fmaf(wr[0], r[0], acc);
        acc = fmaf(wr[1], r[1], acc);
        acc = fmaf(wr[2], r[2], acc);
        acc = fmaf(wr[3], r[3], acc);
        acc = fmaf(wr[4], r[4], acc);
    }
    part[((size_t)cg * BGN + bg) * LL + l0 + li] = acc;
}

// ---------------------------------------------------------------------------
// Offsets stage 2: combine partials, bias/padding cases, tanh -> iy
// ---------------------------------------------------------------------------
__global__ __launch_bounds__(256) void offsets_finish_kernel(
    const float* __restrict__ part, const float* __restrict__ wc,
    float* __restrict__ offv)
{
    int i = blockIdx.x * 256 + threadIdx.x;    // over BGN*LL
    int bg = i >> 12;
    int l  = i & (LL - 1);
    float acc;
    if (l < 2) {
        acc = wc[GCC * KW + 1];                 // conv1 zero-padding region
    } else {
        acc = wc[GCC * KW]
            + part[((size_t)0 * BGN + bg) * LL + l]
            + part[((size_t)1 * BGN + bg) * LL + l]
            + part[((size_t)2 * BGN + bg) * LL + l]
            + part[((size_t)3 * BGN + bg) * LL + l];
    }
    float off = tanhf(acc) * (float)KW;
    float vg  = (float)l + off;
    float iy  = vg * ((float)LL / (float)(LL + 2 * (KW / 2) - 1)) - 0.5f;
    offv[(size_t)bg * LL + l] = iy;
}

// ---------------------------------------------------------------------------
// Bilinear gather -> xs in [B, L, C] layout, written as bf16 hi/lo pair
// ---------------------------------------------------------------------------
__global__ __launch_bounds__(256) void gather_kernel(
    const float* __restrict__ x, const float* __restrict__ offv,
    unsigned short* __restrict__ xshi, unsigned short* __restrict__ xslo)
{
    int bg = blockIdx.y;
    int b = bg >> 2, g = bg & 3;
    int l  = blockIdx.x * 8 + (threadIdx.x >> 5);
    int d4 = (threadIdx.x & 31) * 4;

    float iy = offv[(size_t)bg * LL + l];
    float fi = floorf(iy);
    float w1 = iy - fi;
    int i0 = (int)fi;
    int i1 = i0 + 1;

    const float* xb = x + (size_t)b * LL * CC + (size_t)g * GCC + d4;
    float4 v0 = make_float4(0.f, 0.f, 0.f, 0.f);
    float4 v1 = make_float4(0.f, 0.f, 0.f, 0.f);
    if (i0 >= 0 && i0 < LL) v0 = *(const float4*)(xb + (size_t)i0 * CC);
    if (i1 >= 0 && i1 < LL) v1 = *(const float4*)(xb + (size_t)i1 * CC);
    float w0 = 1.f - w1;
    float4 r = make_float4(v0.x * w0 + v1.x * w1, v0.y * w0 + v1.y * w1,
                           v0.z * w0 + v1.z * w1, v0.w * w0 + v1.w * w1);
    size_t o = ((size_t)b * LL + l) * CC + (size_t)g * GCC + d4;
    ushort4 h, lo4;
    split2(r.x, h.x, lo4.x); split2(r.y, h.y, lo4.y);
    split2(r.z, h.z, lo4.z); split2(r.w, h.w, lo4.w);
    *(ushort4*)(xshi + o) = h;
    *(ushort4*)(xslo + o) = lo4;
}

// ---------------------------------------------------------------------------
// Attention logits, split-K (fp32 vector; small op)
// ---------------------------------------------------------------------------
__global__ __launch_bounds__(64) void qk_logits(
    const float* __restrict__ q, const float* __restrict__ k,
    float* __restrict__ part)
{
    int ks = blockIdx.x, bh = blockIdx.y;
    int b = bh >> 4, h = bh & 15;
    int lane = threadIdx.x;
    int ti = lane >> 3, tj = lane & 7;
    const float* qb = q + ((size_t)b * CC + h * HCC + ti * 4) * LL;
    const float* kb = k + ((size_t)b * CC + h * HCC + tj * 4) * LL;

    float acc[4][4];
#pragma unroll
    for (int i = 0; i < 4; ++i)
#pragma unroll
        for (int j = 0; j < 4; ++j) acc[i][j] = 0.f;

    const int chunk = LL / KSPLIT;
    int l0 = ks * chunk;
    for (int l = l0; l < l0 + chunk; l += 8) {
        float4 qa[4][2], kv[4][2];
#pragma unroll
        for (int p = 0; p < 4; ++p) {
            qa[p][0] = *(const float4*)(qb + (size_t)p * LL + l);
            qa[p][1] = *(const float4*)(qb + (size_t)p * LL + l + 4);
            kv[p][0] = *(const float4*)(kb + (size_t)p * LL + l);
            kv[p][1] = *(const float4*)(kb + (size_t)p * LL + l + 4);
        }
#pragma unroll
        for (int i = 0; i < 4; ++i)
#pragma unroll
            for (int j = 0; j < 4; ++j) {
                float s = acc[i][j];
                s = fmaf(qa[i][0].x, kv[j][0].x, s);
                s = fmaf(qa[i][0].y, kv[j][0].y, s);
                s = fmaf(qa[i][0].z, kv[j][0].z, s);
                s = fmaf(qa[i][0].w, kv[j][0].w, s);
                s = fmaf(qa[i][1].x, kv[j][1].x, s);
                s = fmaf(qa[i][1].y, kv[j][1].y, s);
                s = fmaf(qa[i][1].z, kv[j][1].z, s);
                s = fmaf(qa[i][1].w, kv[j][1].w, s);
                acc[i][j] = s;
            }
    }
#pragma unroll
    for (int i = 0; i < 4; ++i)
#pragma unroll
        for (int j = 0; j < 4; ++j)
            part[(((size_t)bh * KSPLIT + ks) * HCC + ti * 4 + i) * HCC + tj * 4 + j] = acc[i][j];
}

__global__ __launch_bounds__(64) void softmax_kernel(
    const float* __restrict__ part, float* __restrict__ attn)
{
    int bh = blockIdx.x;
    int i = threadIdx.x;
    if (i >= HCC) return;
    const float SCALE = 0.044194173824159216f;  // 512^-0.5

    float lg[HCC];
    float mx = -1e30f;
#pragma unroll
    for (int j = 0; j < HCC; ++j) {
        float s = 0.f;
        for (int ks = 0; ks < KSPLIT; ++ks)
            s += part[(((size_t)bh * KSPLIT + ks) * HCC + i) * HCC + j];
        s *= SCALE;
        lg[j] = s;
        mx = fmaxf(mx, s);
    }
    float sum = 0.f;
#pragma unroll
    for (int j = 0; j < HCC; ++j) {
        float e = expf(lg[j] - mx);
        lg[j] = e;
        sum += e;
    }
    float inv = 1.f / sum;
#pragma unroll
    for (int j = 0; j < HCC; ++j)
        attn[((size_t)bh * HCC + i) * HCC + j] = lg[j] * inv;
}

// ---------------------------------------------------------------------------
// o[bh,i,l] = sum_j attn[i,j]*v[bh,j,l], -> final [B,L,C] layout as bf16 pair
// ---------------------------------------------------------------------------
__global__ __launch_bounds__(256) void attn_v_kernel(
    const float* __restrict__ attn, const float* __restrict__ v,
    unsigned short* __restrict__ ohi, unsigned short* __restrict__ olo)
{
    int bh = blockIdx.y;
    int b = bh >> 4, h = bh & 15;
    int tid = threadIdx.x;
    int i = tid >> 3, lsub = tid & 7;

    float arow[HCC];
#pragma unroll
    for (int j = 0; j < HCC; ++j)
        arow[j] = attn[((size_t)bh * HCC + i) * HCC + j];

    const float* vb = v + ((size_t)b * CC + h * HCC) * LL;
    __shared__ float os[HCC][65];

    for (int l0 = blockIdx.x * 512; l0 < blockIdx.x * 512 + 512; l0 += 64) {
        int lbase = l0 + lsub * 8;
        float4 a0 = make_float4(0.f, 0.f, 0.f, 0.f);
        float4 a1 = make_float4(0.f, 0.f, 0.f, 0.f);
#pragma unroll 8
        for (int j = 0; j < HCC; ++j) {
            float aw = arow[j];
            float4 v0 = *(const float4*)(vb + (size_t)j * LL + lbase);
            float4 v1 = *(const float4*)(vb + (size_t)j * LL + lbase + 4);
            a0.x = fmaf(aw, v0.x, a0.x); a0.y = fmaf(aw, v0.y, a0.y);
            a0.z = fmaf(aw, v0.z, a0.z); a0.w = fmaf(aw, v0.w, a0.w);
            a1.x = fmaf(aw, v1.x, a1.x); a1.y = fmaf(aw, v1.y, a1.y);
            a1.z = fmaf(aw, v1.z, a1.z); a1.w = fmaf(aw, v1.w, a1.w);
        }
        os[i][lsub*8+0] = a0.x; os[i][lsub*8+1] = a0.y;
        os[i][lsub*8+2] = a0.z; os[i][lsub*8+3] = a0.w;
        os[i][lsub*8+4] = a1.x; os[i][lsub*8+5] = a1.y;
        os[i][lsub*8+6] = a1.z; os[i][lsub*8+7] = a1.w;
        __syncthreads();
        int i2 = tid & 31, lw = tid >> 5;
#pragma unroll
        for (int c = 0; c < 8; ++c) {
            int ll = lw * 8 + c;
            float val = os[i2][ll];
            unsigned short hbits, lbits;
            split2(val, hbits, lbits);
            size_t oidx = ((size_t)b * LL + l0 + ll) * CC + h * HCC + i2;
            ohi[oidx] = hbits;
            olo[oidx] = lbits;
        }
        __syncthreads();
    }
}

// ---------------------------------------------------------------------------
extern "C" void kernel_launch(void* const* d_in, const int* in_sizes, int n_in,
                              void* d_out, int out_size, void* d_ws, size_t ws_size,
                              hipStream_t stream)
{
    (void)in_sizes; (void)n_in; (void)out_size; (void)ws_size;
    const float* x     = (const float*)d_in[0];
    const float* Wq    = (const float*)d_in[1];
    const float* bq    = (const float*)d_in[2];
    const float* Wk    = (const float*)d_in[3];
    const float* bk    = (const float*)d_in[4];
    const float* Wv    = (const float*)d_in[5];
    const float* bv    = (const float*)d_in[6];
    const float* Woff1 = (const float*)d_in[7];
    const float* boff1 = (const float*)d_in[8];
    const float* Woff2 = (const float*)d_in[9];
    const float* boff2 = (const float*)d_in[10];
    const float* rpb   = (const float*)d_in[11];
    const float* Wout  = (const float*)d_in[12];
    const float* bout  = (const float*)d_in[13];
    float* out = (float*)d_out;

    float* ws = (float*)d_ws;
    float* q    = ws;                          // [B,C,L]  8,388,608 f
    float* kbuf = ws + 8388608;                // [B,C,L]  8,388,608 f
    float* vbuf = ws + 16777216;               // [B,C,L]  8,388,608 f
    unsigned short* dhi = (unsigned short*)(ws + 25165824);   // 8,388,608 u16
    unsigned short* dlo = (unsigned short*)(ws + 25165824 + 4194304);
    unsigned short* whi = (unsigned short*)(ws + 33554432);   // 4x262144 u16
    unsigned short* wlo = (unsigned short*)(ws + 33554432 + 524288);
    float* offv = ws + 34603008;               // [BG,L]  65,536
    float* wcmb = ws + 34668544;               // 1,024
    float* part = ws + 34669568;               // [64,16,32,32] 1,048,576 (also offsets partials)
    float* attn = ws + 35718144;               // [64,32,32] 65,536

    const size_t NK = (size_t)LL * CC;   // per-batch activation elems
    const int NOSPLIT = 1 << 20;

    comb_weights<<<dim3(3), dim3(256), 0, stream>>>(Woff1, boff1, Woff2, boff2, wcmb);
    split_w_kernel<<<dim3(256, 4), dim3(256), 0, stream>>>(Wq, Wk, Wv, Wout, whi, wlo);
    split_x_kernel<<<dim3(8192), dim3(256), 0, stream>>>(x, dhi, dlo, 2097152);

    // q = Wq @ x^T -> [B,C,L]
    gemm_split_mfma<<<dim3(32, 4, 4), dim3(256), 0, stream>>>(
        whi + 0 * 262144, wlo + 0 * 262144, whi, wlo, dhi, dlo,
        bq, bq, nullptr, q, q, NOSPLIT,
        CC, LL, CC, 0, NK, 0);

    // offset prediction (two-stage, parallel)
    offsets_part_kernel<<<dim3(32, 16, 4), dim3(128), 0, stream>>>(q, wcmb, part);
    offsets_finish_kernel<<<dim3(256), dim3(256), 0, stream>>>(part, wcmb, offv);
    gather_kernel<<<dim3(512, 16), dim3(256), 0, stream>>>(x, offv, dhi, dlo);

    // k = Wk @ xs^T ; v = Wv @ xs^T + rpb  -- MERGED: 1024 blocks, set2 = v
    gemm_split_mfma<<<dim3(32, 8, 4), dim3(256), 0, stream>>>(
        whi + 1 * 262144, wlo + 1 * 262144,        // set1: Wk
        whi + 2 * 262144, wlo + 2 * 262144,        // set2: Wv
        dhi, dlo, bk, bv, rpb, kbuf, vbuf, 4,
        CC, LL, CC, 0, NK, 0);

    qk_logits<<<dim3(KSPLIT, BHN), dim3(64), 0, stream>>>(q, kbuf, part);
    softmax_kernel<<<dim3(BHN), dim3(64), 0, stream>>>(part, attn);
    attn_v_kernel<<<dim3(8, BHN), dim3(256), 0, stream>>>(attn, vbuf, dhi, dlo);

    // out = o @ Wout^T + bout -> [B,L,C]
    gemm_split_mfma<<<dim3(4, 32, 4), dim3(256), 0, stream>>>(
        dhi, dlo, dhi, dlo, whi + 3 * 262144, wlo + 3 * 262144,
        bout, bout, nullptr, out, out, NOSPLIT,
        LL, CC, CC, NK, 0, 1);
}